// Round 6
// baseline (175.045 us; speedup 1.0000x reference)
//
#include <hip/hip_runtime.h>

typedef _Float16 h2 __attribute__((ext_vector_type(2)));
typedef _Float16 h8 __attribute__((ext_vector_type(8)));
typedef __fp16 fp16x2 __attribute__((ext_vector_type(2)));
typedef float f32x4 __attribute__((ext_vector_type(4)));
typedef float f32x2 __attribute__((ext_vector_type(2)));

#define TB 512
#define GROUPS 4
#define WAVES (TB / 64)
#define PTS_PER_BLOCK (WAVES * GROUPS * 16)   // 512 -> 2048 blocks at M=1M

// pack two f32 -> two f16 (RTZ) in one v_cvt_pkrtz_f16_f32; return raw bits
__device__ __forceinline__ unsigned int pkh(float a, float b) {
  union { fp16x2 h; unsigned int u; } cv;
  cv.h = __builtin_amdgcn_cvt_pkrtz(a, b);
  return cv.u;
}
__device__ __forceinline__ h2 h2cast(unsigned int u) {
  union { unsigned int u; h2 h; } cv;
  cv.u = u;
  return cv.h;
}
// v_add with DPP row_shr:N (reduce within each 16-lane row, sum -> lane 15)
template <int CTRL>
__device__ __forceinline__ float dpp_add(float v) {
  return v + __int_as_float(
                 __builtin_amdgcn_update_dpp(0, __float_as_int(v), CTRL, 0xf, 0xf, true));
}

__global__ __launch_bounds__(TB, 8) void fused_kernel(
    const float* __restrict__ coords, const float* __restrict__ lines,
    const float* __restrict__ W1, const float* __restrict__ b1,
    const float* __restrict__ W2, const float* __restrict__ b2,
    float* __restrict__ out)
{
  // fp16 tables storing T' = 1 + T/RANGE, row stride 40 halves (80 B).
  // feat = RANGE*(xe'*ye'*ze' - 1): affine part folded into W1/b1 below.
  __shared__ alignas(16) unsigned short tab[3 * 128 * 40]; // 30720 B

  for (int c = threadIdx.x; c < 1920; c += TB) {
    int d = c / 640, rem = c - d * 640, r = rem / 5, s = rem - r * 5;
    uint4 o = make_uint4(0u, 0u, 0u, 0u);
    if (s < 4) {
      const float4* src = (const float4*)(lines + d * 4096 + r * 32 + s * 8);
      float4 f0 = src[0], f1 = src[1];
      o.x = pkh(fmaf(2.5f, f0.x, 1.f), fmaf(2.5f, f0.y, 1.f));
      o.y = pkh(fmaf(2.5f, f0.z, 1.f), fmaf(2.5f, f0.w, 1.f));
      o.z = pkh(fmaf(2.5f, f1.x, 1.f), fmaf(2.5f, f1.y, 1.f));
      o.w = pkh(fmaf(2.5f, f1.z, 1.f), fmaf(2.5f, f1.w, 1.f));
    }
    ((uint4*)tab)[c] = o;
  }

  const int lane = threadIdx.x & 63;
  const int wv   = threadIdx.x >> 6;
  const int col  = lane & 15;   // A-row m (point) / C-col n (hidden unit)
  const int q    = lane >> 4;   // quad: A k-octet / C row-group

  // B-fragments hold 0.4*W1; bias absorbed: b1' = b1 - 0.4*rowsum(W1)
  h8 bfrag[8];
  float b1p[8], w2s[8];
  #pragma unroll
  for (int t = 0; t < 8; ++t) {
    const float4* wr = (const float4*)(W1 + (col + 16 * t) * 32 + q * 8);
    float4 w0 = wr[0], w1 = wr[1];
    union { uint4 u; h8 v; } cv;
    cv.u.x = pkh(0.4f * w0.x, 0.4f * w0.y);
    cv.u.y = pkh(0.4f * w0.z, 0.4f * w0.w);
    cv.u.z = pkh(0.4f * w1.x, 0.4f * w1.y);
    cv.u.w = pkh(0.4f * w1.z, 0.4f * w1.w);
    bfrag[t] = cv.v;
    float s8 = ((w0.x + w0.y) + (w0.z + w0.w)) + ((w1.x + w1.y) + (w1.z + w1.w));
    s8 += __shfl_xor(s8, 16, 64);    // sum across the 4 q-lanes of this row
    s8 += __shfl_xor(s8, 32, 64);
    b1p[t] = b1[col + 16 * t] - 0.4f * s8;
    w2s[t] = W2[col + 16 * t];
  }
  const float vb2c = b2[0] * 0.0625f;  // b2 enters via the 16-lane DPP sum
  __syncthreads();

  const char* tbase = (const char*)tab + q * 16; // lane's 16B chunk in a row
  const int wave_base = blockIdx.x * PTS_PER_BLOCK + wv * (GROUPS * 16);

  // coord prefetch for group 0
  const float* cp0 = coords + (wave_base + col) * 3;
  float ncx = cp0[0], ncy = cp0[1], ncz = cp0[2];

  #pragma unroll 2
  for (int g = 0; g < GROUPS; ++g) {
    const int p0 = wave_base + g * 16;
    const float cx = ncx, cy = ncy, cz = ncz;
    if (g + 1 < GROUPS) {   // prefetch next group's coords
      const float* np = coords + (p0 + 16 + col) * 3;
      ncx = np[0]; ncy = np[1]; ncz = np[2];
    }

    // align_corners bilinear setup (coords in [-1,1) so both taps in range)
    const float posx = (cx + 1.0f) * 63.5f;
    const float posy = (cy + 1.0f) * 63.5f;
    const float posz = (cz + 1.0f) * 63.5f;
    const int ix = (int)posx;
    const int iy = (int)posy;
    const int iz = (int)posz;
    const float frx = posx - (float)ix;
    const float fry = posy - (float)iy;
    const float frz = posz - (float)iz;
    const h2 fx = h2cast(pkh(frx, frx));
    const h2 fy = h2cast(pkh(fry, fry));
    const h2 fz = h2cast(pkh(frz, frz));

    const uint4* gx = (const uint4*)(tbase + ix * 80);
    const uint4* gy = (const uint4*)(tbase + 10240 + iy * 80);
    const uint4* gz = (const uint4*)(tbase + 20480 + iz * 80);
    union { uint4 u; h2 h[4]; } X0, X1, Y0, Y1, Z0, Z1;
    X0.u = gx[0]; X1.u = gx[5];   // offset:80 = next row
    Y0.u = gy[0]; Y1.u = gy[5];
    Z0.u = gz[0]; Z1.u = gz[5];

    // feat A-frag = product of three lerps (tables hold 1 + T/RANGE)
    union { h8 v; h2 h[4]; } av;
    #pragma unroll
    for (int k = 0; k < 4; ++k) {
      h2 xa = X0.h[k], xb = X1.h[k];
      h2 ya = Y0.h[k], yb = Y1.h[k];
      h2 za = Z0.h[k], zb = Z1.h[k];
      h2 xe = xa + fx * (xb - xa);
      h2 ye = ya + fy * (yb - ya);
      h2 ze = za + fz * (zb - za);
      av.h[k] = xe * ye * ze;
    }

    // MFMA (zero C) + fused bias/relu/W2 epilogue
    const f32x4 z4 = {0.f, 0.f, 0.f, 0.f};
    f32x2 a01 = {vb2c, vb2c}, a23 = {vb2c, vb2c};
    #pragma unroll
    for (int t = 0; t < 8; ++t) {
      f32x4 c = __builtin_amdgcn_mfma_f32_16x16x32_f16(av.v, bfrag[t], z4, 0, 0, 0);
      f32x2 h01 = __builtin_elementwise_max(c.xy + b1p[t], (f32x2){0.f, 0.f});
      f32x2 h23 = __builtin_elementwise_max(c.zw + b1p[t], (f32x2){0.f, 0.f});
      a01 += h01 * w2s[t];
      a23 += h23 * w2s[t];
    }

    // reduce over the 16 col-lanes with DPP row_shr (sum lands in lane 15)
    float s0 = a01.x, s1v = a01.y, s2 = a23.x, s3 = a23.y;
    s0  = dpp_add<0x118>(dpp_add<0x114>(dpp_add<0x112>(dpp_add<0x111>(s0))));
    s1v = dpp_add<0x118>(dpp_add<0x114>(dpp_add<0x112>(dpp_add<0x111>(s1v))));
    s2  = dpp_add<0x118>(dpp_add<0x114>(dpp_add<0x112>(dpp_add<0x111>(s2))));
    s3  = dpp_add<0x118>(dpp_add<0x114>(dpp_add<0x112>(dpp_add<0x111>(s3))));
    if (col == 15) {   // lane 15 of quad q stores points p0 + q*4 .. +3
      *((float4*)(out + p0 + q * 4)) = make_float4(s0, s1v, s2, s3);
    }
  }
}

extern "C" void kernel_launch(void* const* d_in, const int* in_sizes, int n_in,
                              void* d_out, int out_size, void* d_ws, size_t ws_size,
                              hipStream_t stream) {
  const float* coords = (const float*)d_in[0];
  const float* lines  = (const float*)d_in[1];
  const float* W1     = (const float*)d_in[2];
  const float* b1     = (const float*)d_in[3];
  const float* W2     = (const float*)d_in[4];
  const float* b2     = (const float*)d_in[5];
  float* out = (float*)d_out;
  const int M = in_sizes[0] / 3;

  const int blocks = (M + PTS_PER_BLOCK - 1) / PTS_PER_BLOCK;
  fused_kernel<<<blocks, TB, 0, stream>>>(coords, lines, W1, b1, W2, b2, out);
}

// Round 7
// 118.649 us; speedup vs baseline: 1.4753x; 1.4753x over previous
//
#include <hip/hip_runtime.h>

typedef _Float16 h2 __attribute__((ext_vector_type(2)));
typedef _Float16 h8 __attribute__((ext_vector_type(8)));
typedef __fp16 fp16x2 __attribute__((ext_vector_type(2)));
typedef float f32x4 __attribute__((ext_vector_type(4)));
typedef float f32x2 __attribute__((ext_vector_type(2)));

#define TB 512
#define GROUPS 4
#define WAVES (TB / 64)
#define PTS_PER_BLOCK (WAVES * GROUPS * 16)   // 512 -> 2048 blocks at M=1M

// pack two f32 -> two f16 (RTZ) in one v_cvt_pkrtz_f16_f32; return raw bits
__device__ __forceinline__ unsigned int pkh(float a, float b) {
  union { fp16x2 h; unsigned int u; } cv;
  cv.h = __builtin_amdgcn_cvt_pkrtz(a, b);
  return cv.u;
}
__device__ __forceinline__ h2 h2cast(unsigned int u) {
  union { unsigned int u; h2 h; } cv;
  cv.u = u;
  return cv.h;
}
// v_add with DPP row_shr:N (reduce within each 16-lane row, sum -> lane 15)
template <int CTRL>
__device__ __forceinline__ float dpp_add(float v) {
  return v + __int_as_float(
                 __builtin_amdgcn_update_dpp(0, __float_as_int(v), CTRL, 0xf, 0xf, true));
}

// NOTE: plain __launch_bounds__(TB) ONLY. The min-waves/EU second argument
// caps VGPRs below this kernel's natural ~60 and forces scratch spill
// (R2: 48 VGPR -> 46 MB writes; R6: 32 VGPR -> 127 MB writes, 2.7x slower).
__global__ __launch_bounds__(TB) void fused_kernel(
    const float* __restrict__ coords, const float* __restrict__ lines,
    const float* __restrict__ W1, const float* __restrict__ b1,
    const float* __restrict__ W2, const float* __restrict__ b2,
    float* __restrict__ out)
{
  // fp16 tables storing T' = 1 + T/RANGE, row stride 40 halves (80 B).
  // feat = RANGE*(xe'*ye'*ze' - 1): affine part folded into W1/b1 below.
  __shared__ alignas(16) unsigned short tab[3 * 128 * 40]; // 30720 B

  for (int c = threadIdx.x; c < 1920; c += TB) {
    int d = c / 640, rem = c - d * 640, r = rem / 5, s = rem - r * 5;
    uint4 o = make_uint4(0u, 0u, 0u, 0u);
    if (s < 4) {
      const float4* src = (const float4*)(lines + d * 4096 + r * 32 + s * 8);
      float4 f0 = src[0], f1 = src[1];
      o.x = pkh(fmaf(2.5f, f0.x, 1.f), fmaf(2.5f, f0.y, 1.f));
      o.y = pkh(fmaf(2.5f, f0.z, 1.f), fmaf(2.5f, f0.w, 1.f));
      o.z = pkh(fmaf(2.5f, f1.x, 1.f), fmaf(2.5f, f1.y, 1.f));
      o.w = pkh(fmaf(2.5f, f1.z, 1.f), fmaf(2.5f, f1.w, 1.f));
    }
    ((uint4*)tab)[c] = o;
  }

  const int lane = threadIdx.x & 63;
  const int wv   = threadIdx.x >> 6;
  const int col  = lane & 15;   // A-row m (point) / C-col n (hidden unit)
  const int q    = lane >> 4;   // quad: A k-octet / C row-group

  // B-fragments hold 0.4*W1; bias absorbed: b1' = b1 - 0.4*rowsum(W1)
  h8 bfrag[8];
  float b1p[8], w2s[8];
  #pragma unroll
  for (int t = 0; t < 8; ++t) {
    const float4* wr = (const float4*)(W1 + (col + 16 * t) * 32 + q * 8);
    float4 w0 = wr[0], w1 = wr[1];
    union { uint4 u; h8 v; } cv;
    cv.u.x = pkh(0.4f * w0.x, 0.4f * w0.y);
    cv.u.y = pkh(0.4f * w0.z, 0.4f * w0.w);
    cv.u.z = pkh(0.4f * w1.x, 0.4f * w1.y);
    cv.u.w = pkh(0.4f * w1.z, 0.4f * w1.w);
    bfrag[t] = cv.v;
    float s8 = ((w0.x + w0.y) + (w0.z + w0.w)) + ((w1.x + w1.y) + (w1.z + w1.w));
    s8 += __shfl_xor(s8, 16, 64);    // sum across the 4 q-lanes of this row
    s8 += __shfl_xor(s8, 32, 64);
    b1p[t] = b1[col + 16 * t] - 0.4f * s8;
    w2s[t] = W2[col + 16 * t];
  }
  const float vb2c = b2[0] * 0.0625f;  // b2 enters via the 16-lane DPP sum
  __syncthreads();

  const char* tbase = (const char*)tab + q * 16; // lane's 16B chunk in a row
  const int wave_base = blockIdx.x * PTS_PER_BLOCK + wv * (GROUPS * 16);

  // coord prefetch for group 0
  const float* cp0 = coords + (wave_base + col) * 3;
  float ncx = cp0[0], ncy = cp0[1], ncz = cp0[2];

  #pragma unroll 2
  for (int g = 0; g < GROUPS; ++g) {
    const int p0 = wave_base + g * 16;
    const float cx = ncx, cy = ncy, cz = ncz;
    if (g + 1 < GROUPS) {   // prefetch next group's coords
      const float* np = coords + (p0 + 16 + col) * 3;
      ncx = np[0]; ncy = np[1]; ncz = np[2];
    }

    // align_corners bilinear setup (coords in [-1,1) so both taps in range)
    const float posx = (cx + 1.0f) * 63.5f;
    const float posy = (cy + 1.0f) * 63.5f;
    const float posz = (cz + 1.0f) * 63.5f;
    const int ix = (int)posx;
    const int iy = (int)posy;
    const int iz = (int)posz;
    const float frx = posx - (float)ix;
    const float fry = posy - (float)iy;
    const float frz = posz - (float)iz;
    const h2 fx = h2cast(pkh(frx, frx));
    const h2 fy = h2cast(pkh(fry, fry));
    const h2 fz = h2cast(pkh(frz, frz));

    const uint4* gx = (const uint4*)(tbase + ix * 80);
    const uint4* gy = (const uint4*)(tbase + 10240 + iy * 80);
    const uint4* gz = (const uint4*)(tbase + 20480 + iz * 80);
    union { uint4 u; h2 h[4]; } X0, X1, Y0, Y1, Z0, Z1;
    X0.u = gx[0]; X1.u = gx[5];   // offset:80 = next row
    Y0.u = gy[0]; Y1.u = gy[5];
    Z0.u = gz[0]; Z1.u = gz[5];

    // feat A-frag = product of three lerps (tables hold 1 + T/RANGE)
    union { h8 v; h2 h[4]; } av;
    #pragma unroll
    for (int k = 0; k < 4; ++k) {
      h2 xa = X0.h[k], xb = X1.h[k];
      h2 ya = Y0.h[k], yb = Y1.h[k];
      h2 za = Z0.h[k], zb = Z1.h[k];
      h2 xe = xa + fx * (xb - xa);
      h2 ye = ya + fy * (yb - ya);
      h2 ze = za + fz * (zb - za);
      av.h[k] = xe * ye * ze;
    }

    // MFMA (zero C) + fused bias/relu/W2 epilogue
    const f32x4 z4 = {0.f, 0.f, 0.f, 0.f};
    f32x2 a01 = {vb2c, vb2c}, a23 = {vb2c, vb2c};
    #pragma unroll
    for (int t = 0; t < 8; ++t) {
      f32x4 c = __builtin_amdgcn_mfma_f32_16x16x32_f16(av.v, bfrag[t], z4, 0, 0, 0);
      f32x2 h01 = __builtin_elementwise_max(c.xy + b1p[t], (f32x2){0.f, 0.f});
      f32x2 h23 = __builtin_elementwise_max(c.zw + b1p[t], (f32x2){0.f, 0.f});
      a01 += h01 * w2s[t];
      a23 += h23 * w2s[t];
    }

    // reduce over the 16 col-lanes with DPP row_shr (sum lands in lane 15)
    float s0 = a01.x, s1v = a01.y, s2 = a23.x, s3 = a23.y;
    s0  = dpp_add<0x118>(dpp_add<0x114>(dpp_add<0x112>(dpp_add<0x111>(s0))));
    s1v = dpp_add<0x118>(dpp_add<0x114>(dpp_add<0x112>(dpp_add<0x111>(s1v))));
    s2  = dpp_add<0x118>(dpp_add<0x114>(dpp_add<0x112>(dpp_add<0x111>(s2))));
    s3  = dpp_add<0x118>(dpp_add<0x114>(dpp_add<0x112>(dpp_add<0x111>(s3))));
    if (col == 15) {   // lane 15 of quad q stores points p0 + q*4 .. +3
      *((float4*)(out + p0 + q * 4)) = make_float4(s0, s1v, s2, s3);
    }
  }
}

extern "C" void kernel_launch(void* const* d_in, const int* in_sizes, int n_in,
                              void* d_out, int out_size, void* d_ws, size_t ws_size,
                              hipStream_t stream) {
  const float* coords = (const float*)d_in[0];
  const float* lines  = (const float*)d_in[1];
  const float* W1     = (const float*)d_in[2];
  const float* b1     = (const float*)d_in[3];
  const float* W2     = (const float*)d_in[4];
  const float* b2     = (const float*)d_in[5];
  float* out = (float*)d_out;
  const int M = in_sizes[0] / 3;

  const int blocks = (M + PTS_PER_BLOCK - 1) / PTS_PER_BLOCK;
  fused_kernel<<<blocks, TB, 0, stream>>>(coords, lines, W1, b1, W2, b2, out);
}

// Round 8
// 96.724 us; speedup vs baseline: 1.8097x; 1.2267x over previous
//
#include <hip/hip_runtime.h>

typedef _Float16 h2 __attribute__((ext_vector_type(2)));
typedef _Float16 h8 __attribute__((ext_vector_type(8)));
typedef __fp16 fp16x2 __attribute__((ext_vector_type(2)));
typedef float f32x4 __attribute__((ext_vector_type(4)));
typedef float f32x2 __attribute__((ext_vector_type(2)));

#define TB 512
#define GROUPS 8
#define WAVES (TB / 64)
#define PTS_PER_BLOCK (WAVES * GROUPS * 16)   // 1024 -> 1024 blocks at M=1M

// ws layout (bytes): [0,30720) fp16 table  [30720,38912) W1 fragments
//                    [38912,39424) b1p
#define WS_TAB 0
#define WS_W1 30720
#define WS_B1 38912

// pack two f32 -> two f16 (RTZ) in one v_cvt_pkrtz_f16_f32; return raw bits
__device__ __forceinline__ unsigned int pkh(float a, float b) {
  union { fp16x2 h; unsigned int u; } cv;
  cv.h = __builtin_amdgcn_cvt_pkrtz(a, b);
  return cv.u;
}
__device__ __forceinline__ h2 h2cast(unsigned int u) {
  union { unsigned int u; h2 h; } cv;
  cv.u = u;
  return cv.h;
}
// v_add with DPP row_shr:N (reduce within each 16-lane row, sum -> lane 15)
template <int CTRL>
__device__ __forceinline__ float dpp_add(float v) {
  return v + __int_as_float(
                 __builtin_amdgcn_update_dpp(0, __float_as_int(v), CTRL, 0xf, 0xf, true));
}

// One-block prep: runs once per call (~µs). Produces everything the main
// kernel's prologue needs so blocks don't re-convert fp32 lines/W1 (R7
// lesson: per-block prologue L2 traffic + convert VALU was the regression).
__global__ __launch_bounds__(512) void prep_kernel(
    const float* __restrict__ lines, const float* __restrict__ W1,
    const float* __restrict__ b1, unsigned char* __restrict__ ws)
{
  const int tid = threadIdx.x;
  uint4* wsTab = (uint4*)(ws + WS_TAB);
  uint4* wsW   = (uint4*)(ws + WS_W1);
  float* wsB   = (float*)(ws + WS_B1);

  // fp16 tables storing T' = 1 + T/RANGE, row stride 40 halves (80 B):
  // 16B chunks aligned; row position (5r+q) mod 8 spreads bank quads.
  for (int c = tid; c < 1920; c += 512) {
    int d = c / 640, rem = c - d * 640, r = rem / 5, s = rem - r * 5;
    uint4 o = make_uint4(0u, 0u, 0u, 0u);
    if (s < 4) {
      const float4* src = (const float4*)(lines + d * 4096 + r * 32 + s * 8);
      float4 f0 = src[0], f1 = src[1];
      o.x = pkh(fmaf(2.5f, f0.x, 1.f), fmaf(2.5f, f0.y, 1.f));
      o.y = pkh(fmaf(2.5f, f0.z, 1.f), fmaf(2.5f, f0.w, 1.f));
      o.z = pkh(fmaf(2.5f, f1.x, 1.f), fmaf(2.5f, f1.y, 1.f));
      o.w = pkh(fmaf(2.5f, f1.z, 1.f), fmaf(2.5f, f1.w, 1.f));
    }
    wsTab[c] = o;
  }

  // B-fragments of 0.4*W1 in lane-linear order: wsW[t*64 + (q*16+col)]
  {
    const int t = tid >> 6, q = (tid >> 4) & 3, col = tid & 15;
    const float4* wr = (const float4*)(W1 + (col + 16 * t) * 32 + q * 8);
    float4 w0 = wr[0], w1 = wr[1];
    uint4 o;
    o.x = pkh(0.4f * w0.x, 0.4f * w0.y);
    o.y = pkh(0.4f * w0.z, 0.4f * w0.w);
    o.z = pkh(0.4f * w1.x, 0.4f * w1.y);
    o.w = pkh(0.4f * w1.z, 0.4f * w1.w);
    wsW[tid] = o;
  }

  // b1p[h] = b1[h] - 0.4 * rowsum(W1[h])  (absorbs the affine feat shift)
  if (tid < 128) {
    const float* r = W1 + tid * 32;
    float s = 0.f;
    #pragma unroll
    for (int k = 0; k < 32; ++k) s += r[k];
    wsB[tid] = b1[tid] - 0.4f * s;
  }
}

// NOTE: plain __launch_bounds__(TB) ONLY. The min-waves/EU second argument
// caps VGPRs below this kernel's natural ~60 and forces scratch spill
// (R2: 48 VGPR -> 46 MB writes; R6: 32 VGPR -> 127 MB writes, 2.7x slower).
__global__ __launch_bounds__(TB) void fused_kernel(
    const float* __restrict__ coords, const unsigned char* __restrict__ ws,
    const float* __restrict__ W2, const float* __restrict__ b2,
    float* __restrict__ out)
{
  __shared__ alignas(16) unsigned short tab[3 * 128 * 40]; // 30720 B

  // Prologue is now a straight copy (no convert): 30.7 KB from L2.
  {
    const uint4* src = (const uint4*)(ws + WS_TAB);
    uint4* dst = (uint4*)tab;
    for (int c = threadIdx.x; c < 1920; c += TB) dst[c] = src[c];
  }

  const int lane = threadIdx.x & 63;
  const int wv   = threadIdx.x >> 6;
  const int col  = lane & 15;   // A-row m (point) / C-col n (hidden unit)
  const int q    = lane >> 4;   // quad: A k-octet / C row-group

  // Fragment loads: wsW[t*64 + lane] is coalesced per wave, L1-hot (8 KB).
  const uint4* wsW = (const uint4*)(ws + WS_W1);
  const float* wsB = (const float*)(ws + WS_B1);
  h8 bfrag[8];
  float b1p[8], w2s[8];
  #pragma unroll
  for (int t = 0; t < 8; ++t) {
    union { uint4 u; h8 v; } cv;
    cv.u = wsW[t * 64 + lane];
    bfrag[t] = cv.v;
    b1p[t] = wsB[col + 16 * t];
    w2s[t] = W2[col + 16 * t];
  }
  const float vb2c = b2[0] * 0.0625f;  // b2 enters via the 16-lane DPP sum
  __syncthreads();

  const char* tbase = (const char*)tab + q * 16; // lane's 16B chunk in a row
  const int wave_base = blockIdx.x * PTS_PER_BLOCK + wv * (GROUPS * 16);

  // coord prefetch for group 0
  const float* cp0 = coords + (wave_base + col) * 3;
  float ncx = cp0[0], ncy = cp0[1], ncz = cp0[2];

  #pragma unroll 2
  for (int g = 0; g < GROUPS; ++g) {
    const int p0 = wave_base + g * 16;
    const float cx = ncx, cy = ncy, cz = ncz;
    if (g + 1 < GROUPS) {   // prefetch next group's coords
      const float* np = coords + (p0 + 16 + col) * 3;
      ncx = np[0]; ncy = np[1]; ncz = np[2];
    }

    // align_corners bilinear setup (coords in [-1,1) so both taps in range)
    const float posx = (cx + 1.0f) * 63.5f;
    const float posy = (cy + 1.0f) * 63.5f;
    const float posz = (cz + 1.0f) * 63.5f;
    const int ix = (int)posx;
    const int iy = (int)posy;
    const int iz = (int)posz;
    const float frx = posx - (float)ix;
    const float fry = posy - (float)iy;
    const float frz = posz - (float)iz;
    const h2 fx = h2cast(pkh(frx, frx));
    const h2 fy = h2cast(pkh(fry, fry));
    const h2 fz = h2cast(pkh(frz, frz));

    const uint4* gx = (const uint4*)(tbase + ix * 80);
    const uint4* gy = (const uint4*)(tbase + 10240 + iy * 80);
    const uint4* gz = (const uint4*)(tbase + 20480 + iz * 80);
    union { uint4 u; h2 h[4]; } X0, X1, Y0, Y1, Z0, Z1;
    X0.u = gx[0]; X1.u = gx[5];   // offset:80 = next row
    Y0.u = gy[0]; Y1.u = gy[5];
    Z0.u = gz[0]; Z1.u = gz[5];

    // feat A-frag = product of three lerps (tables hold 1 + T/RANGE)
    union { h8 v; h2 h[4]; } av;
    #pragma unroll
    for (int k = 0; k < 4; ++k) {
      h2 xa = X0.h[k], xb = X1.h[k];
      h2 ya = Y0.h[k], yb = Y1.h[k];
      h2 za = Z0.h[k], zb = Z1.h[k];
      h2 xe = xa + fx * (xb - xa);
      h2 ye = ya + fy * (yb - ya);
      h2 ze = za + fz * (zb - za);
      av.h[k] = xe * ye * ze;
    }

    // MFMA (zero C) + fused bias/relu/W2 epilogue
    const f32x4 z4 = {0.f, 0.f, 0.f, 0.f};
    f32x2 a01 = {vb2c, vb2c}, a23 = {vb2c, vb2c};
    #pragma unroll
    for (int t = 0; t < 8; ++t) {
      f32x4 c = __builtin_amdgcn_mfma_f32_16x16x32_f16(av.v, bfrag[t], z4, 0, 0, 0);
      f32x2 h01 = __builtin_elementwise_max(c.xy + b1p[t], (f32x2){0.f, 0.f});
      f32x2 h23 = __builtin_elementwise_max(c.zw + b1p[t], (f32x2){0.f, 0.f});
      a01 += h01 * w2s[t];
      a23 += h23 * w2s[t];
    }

    // reduce over the 16 col-lanes with DPP row_shr (sum lands in lane 15)
    float s0 = a01.x, s1v = a01.y, s2 = a23.x, s3 = a23.y;
    s0  = dpp_add<0x118>(dpp_add<0x114>(dpp_add<0x112>(dpp_add<0x111>(s0))));
    s1v = dpp_add<0x118>(dpp_add<0x114>(dpp_add<0x112>(dpp_add<0x111>(s1v))));
    s2  = dpp_add<0x118>(dpp_add<0x114>(dpp_add<0x112>(dpp_add<0x111>(s2))));
    s3  = dpp_add<0x118>(dpp_add<0x114>(dpp_add<0x112>(dpp_add<0x111>(s3))));
    if (col == 15) {   // lane 15 of quad q stores points p0 + q*4 .. +3
      *((float4*)(out + p0 + q * 4)) = make_float4(s0, s1v, s2, s3);
    }
  }
}

extern "C" void kernel_launch(void* const* d_in, const int* in_sizes, int n_in,
                              void* d_out, int out_size, void* d_ws, size_t ws_size,
                              hipStream_t stream) {
  const float* coords = (const float*)d_in[0];
  const float* lines  = (const float*)d_in[1];
  const float* W1     = (const float*)d_in[2];
  const float* b1     = (const float*)d_in[3];
  const float* W2     = (const float*)d_in[4];
  const float* b2     = (const float*)d_in[5];
  float* out = (float*)d_out;
  const int M = in_sizes[0] / 3;

  prep_kernel<<<1, 512, 0, stream>>>(lines, W1, b1, (unsigned char*)d_ws);
  const int blocks = (M + PTS_PER_BLOCK - 1) / PTS_PER_BLOCK;
  fused_kernel<<<blocks, TB, 0, stream>>>(coords, (const unsigned char*)d_ws,
                                          W2, b2, out);
}